// Round 16
// baseline (76.001 us; speedup 1.0000x reference)
//
#include <hip/hip_runtime.h>
#include <stdint.h>

// ---------------------------------------------------------------------------
// NeighborSearch: data[n,3], queries[m,3], radius scalar.
// Out layout (int32): [0, m*n)   neighbors_index (compacted front, -1 pad)
//                     [m*n, m*n+m+1) row_splits (exclusive prefix of counts)
//
// Fast path (n==m==8192), 3 nodes:
//   memset: counts = 0.
//   K1 fused_interleave (2048x256): count (proven readlane/ballot) + 10 int4
//     -1 stores/thread covering slabs 22..31 (top 80MB) -- the share of fill
//     that count's VALU time can hide.
//   K3 scanemit_fill (2048x256): per-block scan -> rs, emit [0,L), then fill
//     [Lr/4, 22*SLAB) int4 (~176MB pure-write stream).
//   PARTITION (R15 lesson -- account for all 32 slabs explicitly):
//     emit [0,L) | patch [L,Lr) | K3 [Lr/4, 22*SLAB) | K1 [22*SLAB, 32*SLAB).
//     Max K1 index = 31*SLAB + 524287 = N4TOT-1. Exact, disjoint, complete.
//   (R15 bug: a hidden +SLAB in the base made K1 cover slabs 21..30, leaving
//    slab 31 unwritten -> post-timing poison readback.)
// ---------------------------------------------------------------------------

#define N8 8192
#define SLAB 524288                   // int4 per slab = 2048 blk x 256 thr
#define FEND (22 * SLAB)              // K3 fill end / K1 fill start (int4)
#define N4TOT ((size_t)N8 * N8 / 4)   // 16777216 int4 = 32 slabs

__device__ __forceinline__ float next_up(float x) {
    return __uint_as_float(__float_as_uint(x) + 1u);
}
__device__ __forceinline__ float next_down(float x) {
    return __uint_as_float(__float_as_uint(x) - 1u);
}

// Largest float T such that correctly-rounded sqrt(T) <= r (r > 0).
// (u <= T) <=> (sqrt_rn(max(u,0)) <= r), since sqrt_rn is monotone.
__device__ __forceinline__ float sq_threshold(float r) {
    float T = __fmul_rn(r, r);
    while (__fsqrt_rn(T) > r) T = next_down(T);
    while (__fsqrt_rn(next_up(T)) <= r) T = next_up(T);
    return T;
}

// Reference arithmetic, exactly (no contraction).
__device__ __forceinline__ float pair_metric(float qx, float qy, float qz, float q2,
                                             float dx, float dy, float dz) {
    float d2 = __fadd_rn(__fadd_rn(__fmul_rn(dx, dx), __fmul_rn(dy, dy)),
                         __fmul_rn(dz, dz));
    float dot = __builtin_fmaf(qz, dz, __builtin_fmaf(qy, dy, __fmul_rn(qx, dx)));
    return __fsub_rn(__fadd_rn(q2, d2), __fmul_rn(2.0f, dot));
}

__device__ __forceinline__ float bc_lane(float x, int j) {
    return __int_as_float(__builtin_amdgcn_readlane(__float_as_int(x), j));
}

// ========================= fast path (8192 x 8192) =========================

// Grid: 2048 x 256. Wave unit u = bid*4+wv: chunk c=u>>6 (64 points, lane=
// point), group g=u&63 (queries [g*128,(g+1)*128)). 10 fill stores interleaved.
__global__ __launch_bounds__(256) void fused_interleave(
    const float* __restrict__ data, const float* __restrict__ queries,
    const float* __restrict__ radius_p, int* __restrict__ out_idx,
    unsigned long long* __restrict__ masks, int* __restrict__ counts) {
    int bid = blockIdx.x;
    int tid = threadIdx.x;
    int lane = tid & 63;
    int wv = tid >> 6;
    int u = bid * 4 + wv;
    int c = u >> 6;
    int g = u & 63;

    float T = sq_threshold(radius_p[0]);

    // 64 data points in registers (lane = point)
    int p = c * 64 + lane;
    float dx = data[3 * p + 0], dy = data[3 * p + 1], dz = data[3 * p + 2];
    float d2 = __fadd_rn(__fadd_rn(__fmul_rn(dx, dx), __fmul_rn(dy, dy)),
                         __fmul_rn(dz, dz));

    // both query sections' coords (lane = query within section)
    int q0 = g * 128 + lane, q1 = g * 128 + 64 + lane;
    float qx0 = queries[3 * q0 + 0], qy0 = queries[3 * q0 + 1],
          qz0 = queries[3 * q0 + 2];
    float q20 = __fadd_rn(__fadd_rn(__fmul_rn(qx0, qx0), __fmul_rn(qy0, qy0)),
                          __fmul_rn(qz0, qz0));
    float qx1 = queries[3 * q1 + 0], qy1 = queries[3 * q1 + 1],
          qz1 = queries[3 * q1 + 2];
    float q21 = __fadd_rn(__fadd_rn(__fmul_rn(qx1, qx1), __fmul_rn(qy1, qy1)),
                          __fmul_rn(qz1, qz1));

    unsigned long long parked0 = 0, parked1 = 0;

    int4* out4 = (int4*)out_idx;
    const int4 vm1 = make_int4(-1, -1, -1, -1);
    size_t fb0 = (size_t)bid * 256 + tid;   // plain per-thread offset

    // ---- section 0: j=0..63; at j%13==0 (j<=52) store slab 22+j/13 ----
#pragma unroll
    for (int j = 0; j < 64; ++j) {
        if ((j % 13) == 0 && j <= 52)
            out4[fb0 + (size_t)(22 + j / 13) * SLAB] = vm1;   // slabs 22..26
        float Qx = bc_lane(qx0, j), Qy = bc_lane(qy0, j);
        float Qz = bc_lane(qz0, j), Q2 = bc_lane(q20, j);
        float dot = __builtin_fmaf(Qz, dz,
                      __builtin_fmaf(Qy, dy, __fmul_rn(Qx, dx)));
        float uu = __fsub_rn(__fadd_rn(Q2, d2), __fmul_rn(2.0f, dot));
        unsigned long long mk = __ballot(uu <= T);
        if (lane == j) parked0 = mk;
    }
    // ---- section 1: j=0..63; at j%13==0 (j<=52) store slab 27+j/13 ----
#pragma unroll
    for (int j = 0; j < 64; ++j) {
        if ((j % 13) == 0 && j <= 52)
            out4[fb0 + (size_t)(27 + j / 13) * SLAB] = vm1;   // slabs 27..31
        float Qx = bc_lane(qx1, j), Qy = bc_lane(qy1, j);
        float Qz = bc_lane(qz1, j), Q2 = bc_lane(q21, j);
        float dot = __builtin_fmaf(Qz, dz,
                      __builtin_fmaf(Qy, dy, __fmul_rn(Qx, dx)));
        float uu = __fsub_rn(__fadd_rn(Q2, d2), __fmul_rn(2.0f, dot));
        unsigned long long mk = __ballot(uu <= T);
        if (lane == j) parked1 = mk;
    }

    masks[(size_t)q0 * 128 + c] = parked0;   // query-major (proven R8+)
    masks[(size_t)q1 * 128 + c] = parked1;
    atomicAdd(&counts[q0], __popcll(parked0));
    atomicAdd(&counts[q1], __popcll(parked1));
}

// Grid: 2048 x 256. R12-verbatim scan+emit, then fill [Lr/4, FEND) int4.
__global__ __launch_bounds__(256) void scanemit_fill(
    const unsigned long long* __restrict__ masks, const int* __restrict__ counts,
    int* __restrict__ out_idx, int* __restrict__ rs) {
    __shared__ int part[256];
    __shared__ int s_cnt[32];
    __shared__ int s_base[4];
    int b = blockIdx.x;
    int t = threadIdx.x;
    int wave = t >> 6;
    int lane = t & 63;

    int s = 0;
#pragma unroll 8
    for (int k = 0; k < 32; ++k) s += counts[t * 32 + k];
    part[t] = s;
    __syncthreads();
    for (int off = 1; off < 256; off <<= 1) {
        int v = 0;
        if (t >= off) v = part[t - off];
        __syncthreads();
        if (t >= off) part[t] += v;
        __syncthreads();
    }
    int c32 = b >> 3;
    if (t < 32) s_cnt[t] = counts[c32 * 32 + t];
    __syncthreads();
    if (t < 4) {
        int q = b * 4 + t;
        int excl = (c32 == 0) ? 0 : part[c32 - 1];
        int o = q & 31;
        int sum = 0;
        for (int k = 0; k < o; ++k) sum += s_cnt[k];
        int v = excl + sum;
        s_base[t] = v;
        rs[q] = v;
    }
    if (b == 2047 && t == 0) rs[N8] = part[255];
    __syncthreads();
    int L = part[255];

    {
        int q = b * 4 + wave;
        unsigned long long lo = masks[(size_t)q * 128 + lane];
        unsigned long long hi = masks[(size_t)q * 128 + 64 + lane];
        int plo = __popcll(lo), phi = __popcll(hi);
        int ilo = plo, ihi = phi;
        for (int off = 1; off < 64; off <<= 1) {
            int a = __shfl_up(ilo, off, 64);
            int bsh = __shfl_up(ihi, off, 64);
            if (lane >= off) { ilo += a; ihi += bsh; }
        }
        int total_lo = __shfl(ilo, 63, 64);
        int base = s_base[wave];
        int pos_lo = base + ilo - plo;
        int pos_hi = base + total_lo + ihi - phi;
        int jb_lo = lane * 64, jb_hi = (64 + lane) * 64;
        while (lo) {
            int bt = __builtin_ctzll(lo);
            out_idx[pos_lo++] = jb_lo + bt;
            lo &= lo - 1;
        }
        while (hi) {
            int bt = __builtin_ctzll(hi);
            out_idx[pos_hi++] = jb_hi + bt;
            hi &= hi - 1;
        }
    }

    // ---- fill [Lr/4, FEND) int4 (K1 fills [FEND, N4TOT)) ----
    int Lr = (L + 3) & ~3;
    if (b == 0 && t < (Lr - L)) out_idx[L + t] = -1;
    int4* out4 = (int4*)out_idx;
    const int4 v = make_int4(-1, -1, -1, -1);
    size_t i = (size_t)(Lr >> 2) + (size_t)b * 256 + t;
    for (; i < (size_t)FEND; i += (size_t)SLAB) out4[i] = v;
}

// ====================== generic fallback (round-1 path) ======================

__global__ __launch_bounds__(256) void fill_kernel(int* __restrict__ out, size_t total) {
    size_t n4 = total >> 2;
    int4* out4 = (int4*)out;
    size_t i = (size_t)blockIdx.x * blockDim.x + threadIdx.x;
    size_t stride = (size_t)gridDim.x * blockDim.x;
    const int4 v = make_int4(-1, -1, -1, -1);
    for (; i < n4; i += stride) out4[i] = v;
    if (blockIdx.x == 0 && threadIdx.x == 0) {
        for (size_t k = n4 << 2; k < total; ++k) out[k] = -1;
    }
}

__global__ __launch_bounds__(256) void count_kernel(
    const float* __restrict__ data, const float* __restrict__ queries,
    const float* __restrict__ radius_p, int n, int m, int* __restrict__ counts) {
    int q = (blockIdx.x * blockDim.x + threadIdx.x) >> 6;
    int lane = threadIdx.x & 63;
    if (q >= m) return;
    float r = radius_p[0];
    float T = sq_threshold(r);
    float qx = queries[3 * q + 0], qy = queries[3 * q + 1], qz = queries[3 * q + 2];
    float q2 = __fadd_rn(__fadd_rn(__fmul_rn(qx, qx), __fmul_rn(qy, qy)),
                         __fmul_rn(qz, qz));
    int cnt = 0;
    for (int j = lane; j < n; j += 64) {
        float u = pair_metric(qx, qy, qz, q2, data[3 * j], data[3 * j + 1], data[3 * j + 2]);
        if (u <= T) cnt++;
    }
    for (int off = 32; off > 0; off >>= 1) cnt += __shfl_down(cnt, off, 64);
    if (lane == 0) counts[q] = cnt;
}

__global__ __launch_bounds__(1024) void scan_kernel2(const int* __restrict__ counts,
                                                     int* __restrict__ rs, int m) {
    __shared__ int part[1024];
    int t = threadIdx.x;
    int base = t * 8;
    int c[8];
    int s = 0;
    for (int k = 0; k < 8; ++k) {
        int p = base + k;
        c[k] = (p < m) ? counts[p] : 0;
        s += c[k];
    }
    part[t] = s;
    __syncthreads();
    for (int off = 1; off < 1024; off <<= 1) {
        int v = 0;
        if (t >= off) v = part[t - off];
        __syncthreads();
        if (t >= off) part[t] += v;
        __syncthreads();
    }
    int run = (t == 0) ? 0 : part[t - 1];
    for (int k = 0; k < 8; ++k) {
        int p = base + k;
        if (p < m) rs[p] = run;
        run += c[k];
    }
    if (t == 1023) rs[m] = part[1023];
}

__global__ __launch_bounds__(256) void emit_kernel(
    const float* __restrict__ data, const float* __restrict__ queries,
    const float* __restrict__ radius_p, int n, int m,
    const int* __restrict__ row_splits, int* __restrict__ out_idx) {
    int q = (blockIdx.x * blockDim.x + threadIdx.x) >> 6;
    int lane = threadIdx.x & 63;
    if (q >= m) return;
    float r = radius_p[0];
    float T = sq_threshold(r);
    float qx = queries[3 * q + 0], qy = queries[3 * q + 1], qz = queries[3 * q + 2];
    float q2 = __fadd_rn(__fadd_rn(__fmul_rn(qx, qx), __fmul_rn(qy, qy)),
                         __fmul_rn(qz, qz));
    int base = row_splits[q];
    unsigned long long lane_mask_lt = (lane == 0) ? 0ULL : (~0ULL >> (64 - lane));
    for (int j0 = 0; j0 < n; j0 += 64) {
        int j = j0 + lane;
        bool pred = false;
        if (j < n) {
            float u = pair_metric(qx, qy, qz, q2, data[3 * j], data[3 * j + 1], data[3 * j + 2]);
            pred = (u <= T);
        }
        unsigned long long mask = __ballot(pred);
        if (pred) {
            int pos = base + __popcll(mask & lane_mask_lt);
            out_idx[pos] = j;
        }
        base += __popcll(mask);
    }
}

// ===========================================================================

extern "C" void kernel_launch(void* const* d_in, const int* in_sizes, int n_in,
                              void* d_out, int out_size, void* d_ws, size_t ws_size,
                              hipStream_t stream) {
    const float* data = (const float*)d_in[0];
    const float* queries = (const float*)d_in[1];
    const float* radius = (const float*)d_in[2];
    int n = in_sizes[0] / 3;
    int m = in_sizes[1] / 3;
    int* out = (int*)d_out;
    size_t idx_count = (size_t)m * (size_t)n;
    int* row = out + idx_count;  // m+1 ints

    // ws layout: masks (8MB, query-major) | counts (32KB)
    size_t mask_bytes = (size_t)N8 * 128 * 8;
    size_t need = mask_bytes + N8 * 4;
    bool fast = (n == N8) && (m == N8) && (ws_size >= need);

    if (fast) {
        unsigned long long* masks = (unsigned long long*)d_ws;
        int* counts = (int*)((char*)d_ws + mask_bytes);
        hipMemsetAsync(counts, 0, N8 * sizeof(int), stream);
        fused_interleave<<<2048, 256, 0, stream>>>(data, queries, radius, out,
                                                   masks, counts);
        scanemit_fill<<<2048, 256, 0, stream>>>(masks, counts, out, row);
    } else {
        fill_kernel<<<2048, 256, 0, stream>>>(out, idx_count);
        int blocks = (m * 64 + 255) / 256;
        count_kernel<<<blocks, 256, 0, stream>>>(data, queries, radius, n, m, row);
        scan_kernel2<<<1, 1024, 0, stream>>>(row, row, m);
        emit_kernel<<<blocks, 256, 0, stream>>>(data, queries, radius, n, m, row, out);
    }
}

// Round 17
// 72.307 us; speedup vs baseline: 1.0511x; 1.0511x over previous
//
#include <hip/hip_runtime.h>
#include <stdint.h>

// ---------------------------------------------------------------------------
// NeighborSearch: data[n,3], queries[m,3], radius scalar.
// Out layout (int32): [0, m*n)   neighbors_index (compacted front, -1 pad)
//                     [m*n, m*n+m+1) row_splits (exclusive prefix of counts)
//
// Fast path (n==m==8192), 3 nodes (R14 structure, count reformulated):
//   memset: counts = 0.
//   K1 fused_interleave (2048x256): 31 int4 -1 stores over [C0, 64M)
//     interleaved with counting. NEW count: lane owns ONE QUERY + one point;
//     iterate 64 points broadcast via readlane; set bit j of the lane's OWN
//     mask -- no ballot, no cndmask parking (R16 lesson: ballot-based count
//     is ~30us VALU; it was the hidden cost in every fused variant).
//   K3 scanemit_fill_tail (verbatim R12/R14): per-block scan -> rs, emit
//     [0,L) from query-major masks, tail fill [L, C0).
//   Coverage: emit [0,L) | patch [L,Lr) | K3 [Lr/4, C04) | K1 31 slabs
//     [C04, N4TOT). Max K1 index = C04 + 524287 + 30*SLAB = N4TOT-1. Exact.
// ---------------------------------------------------------------------------

#define N8 8192
#define C0 2097152                    // fill boundary (ints) = 8 MB
#define C04 (C0 / 4)                  // 524288 int4
#define SLAB 524288                   // int4 per slab = 2048 blk x 256 thr
#define N4TOT ((size_t)N8 * N8 / 4)   // 16777216 int4

__device__ __forceinline__ float next_up(float x) {
    return __uint_as_float(__float_as_uint(x) + 1u);
}
__device__ __forceinline__ float next_down(float x) {
    return __uint_as_float(__float_as_uint(x) - 1u);
}

// Largest float T such that correctly-rounded sqrt(T) <= r (r > 0).
// (u <= T) <=> (sqrt_rn(max(u,0)) <= r), since sqrt_rn is monotone.
__device__ __forceinline__ float sq_threshold(float r) {
    float T = __fmul_rn(r, r);
    while (__fsqrt_rn(T) > r) T = next_down(T);
    while (__fsqrt_rn(next_up(T)) <= r) T = next_up(T);
    return T;
}

// Reference arithmetic, exactly (no contraction).
__device__ __forceinline__ float pair_metric(float qx, float qy, float qz, float q2,
                                             float dx, float dy, float dz) {
    float d2 = __fadd_rn(__fadd_rn(__fmul_rn(dx, dx), __fmul_rn(dy, dy)),
                         __fmul_rn(dz, dz));
    float dot = __builtin_fmaf(qz, dz, __builtin_fmaf(qy, dy, __fmul_rn(qx, dx)));
    return __fsub_rn(__fadd_rn(q2, d2), __fmul_rn(2.0f, dot));
}

__device__ __forceinline__ float bc_lane(float x, int j) {
    return __int_as_float(__builtin_amdgcn_readlane(__float_as_int(x), j));
}

// ========================= fast path (8192 x 8192) =========================

// Grid: 2048 x 256. Wave unit u = bid*4+wv: chunk c=u>>6, group g=u&63.
// Lane owns point c*64+lane AND queries g*128+lane / g*128+64+lane.
__global__ __launch_bounds__(256) void fused_interleave(
    const float* __restrict__ data, const float* __restrict__ queries,
    const float* __restrict__ radius_p, int* __restrict__ out_idx,
    unsigned long long* __restrict__ masks, int* __restrict__ counts) {
    int bid = blockIdx.x;
    int tid = threadIdx.x;
    int lane = tid & 63;
    int wv = tid >> 6;
    int u = bid * 4 + wv;
    int c = u >> 6;
    int g = u & 63;

    float T = sq_threshold(radius_p[0]);

    // lane's point (broadcast source for all lanes)
    int p = c * 64 + lane;
    float dx = data[3 * p + 0], dy = data[3 * p + 1], dz = data[3 * p + 2];
    float d2 = __fadd_rn(__fadd_rn(__fmul_rn(dx, dx), __fmul_rn(dy, dy)),
                         __fmul_rn(dz, dz));

    // lane's two queries (one per section)
    int q0 = g * 128 + lane, q1 = g * 128 + 64 + lane;
    float qx0 = queries[3 * q0 + 0], qy0 = queries[3 * q0 + 1],
          qz0 = queries[3 * q0 + 2];
    float q20 = __fadd_rn(__fadd_rn(__fmul_rn(qx0, qx0), __fmul_rn(qy0, qy0)),
                          __fmul_rn(qz0, qz0));
    float qx1 = queries[3 * q1 + 0], qy1 = queries[3 * q1 + 1],
          qz1 = queries[3 * q1 + 2];
    float q21 = __fadd_rn(__fadd_rn(__fmul_rn(qx1, qx1), __fmul_rn(qy1, qy1)),
                          __fmul_rn(qz1, qz1));

    unsigned long long mask0 = 0, mask1 = 0;

    int4* out4 = (int4*)out_idx;
    const int4 vm1 = make_int4(-1, -1, -1, -1);
    size_t fb = (size_t)C04 + (size_t)bid * 256 + tid;   // fill base

    // Fill region [C04, N4TOT) = exactly 31 slabs; stores k = 0..30 only.
    // ---- section 0: point j vs lane's query q0; store k=j/4 at j%4==0 ----
#pragma unroll
    for (int j = 0; j < 64; ++j) {
        if ((j & 3) == 0)
            out4[fb + (size_t)(j >> 2) * SLAB] = vm1;          // k = 0..15
        float Px = bc_lane(dx, j), Py = bc_lane(dy, j);
        float Pz = bc_lane(dz, j), Pd2 = bc_lane(d2, j);
        float dot = __builtin_fmaf(qz0, Pz,
                      __builtin_fmaf(qy0, Py, __fmul_rn(qx0, Px)));
        float uu = __fsub_rn(__fadd_rn(q20, Pd2), __fmul_rn(2.0f, dot));
        if (uu <= T) mask0 |= (1ull << j);
    }
    // ---- section 1: store k=16+j/4 at j%4==0, j<60 (k = 16..30) ----
#pragma unroll
    for (int j = 0; j < 64; ++j) {
        if ((j & 3) == 0 && j < 60)
            out4[fb + (size_t)(16 + (j >> 2)) * SLAB] = vm1;   // k = 16..30
        float Px = bc_lane(dx, j), Py = bc_lane(dy, j);
        float Pz = bc_lane(dz, j), Pd2 = bc_lane(d2, j);
        float dot = __builtin_fmaf(qz1, Pz,
                      __builtin_fmaf(qy1, Py, __fmul_rn(qx1, Px)));
        float uu = __fsub_rn(__fadd_rn(q21, Pd2), __fmul_rn(2.0f, dot));
        if (uu <= T) mask1 |= (1ull << j);
    }

    masks[(size_t)q0 * 128 + c] = mask0;   // query-major (proven R8+)
    masks[(size_t)q1 * 128 + c] = mask1;
    atomicAdd(&counts[q0], __popcll(mask0));
    atomicAdd(&counts[q1], __popcll(mask1));
}

// Grid: 2048 x 256. Verbatim R12/R14: per-block scan + rs + emit + tail fill.
__global__ __launch_bounds__(256) void scanemit_fill_tail(
    const unsigned long long* __restrict__ masks, const int* __restrict__ counts,
    int* __restrict__ out_idx, int* __restrict__ rs) {
    __shared__ int part[256];
    __shared__ int s_cnt[32];
    __shared__ int s_base[4];
    int b = blockIdx.x;
    int t = threadIdx.x;
    int wave = t >> 6;
    int lane = t & 63;

    int s = 0;
#pragma unroll 8
    for (int k = 0; k < 32; ++k) s += counts[t * 32 + k];
    part[t] = s;
    __syncthreads();
    for (int off = 1; off < 256; off <<= 1) {
        int v = 0;
        if (t >= off) v = part[t - off];
        __syncthreads();
        if (t >= off) part[t] += v;
        __syncthreads();
    }
    int c32 = b >> 3;
    if (t < 32) s_cnt[t] = counts[c32 * 32 + t];
    __syncthreads();
    if (t < 4) {
        int q = b * 4 + t;
        int excl = (c32 == 0) ? 0 : part[c32 - 1];
        int o = q & 31;
        int sum = 0;
        for (int k = 0; k < o; ++k) sum += s_cnt[k];
        int v = excl + sum;
        s_base[t] = v;
        rs[q] = v;
    }
    if (b == 2047 && t == 0) rs[N8] = part[255];
    __syncthreads();
    int L = part[255];

    {
        int q = b * 4 + wave;
        unsigned long long lo = masks[(size_t)q * 128 + lane];
        unsigned long long hi = masks[(size_t)q * 128 + 64 + lane];
        int plo = __popcll(lo), phi = __popcll(hi);
        int ilo = plo, ihi = phi;
        for (int off = 1; off < 64; off <<= 1) {
            int a = __shfl_up(ilo, off, 64);
            int bsh = __shfl_up(ihi, off, 64);
            if (lane >= off) { ilo += a; ihi += bsh; }
        }
        int total_lo = __shfl(ilo, 63, 64);
        int base = s_base[wave];
        int pos_lo = base + ilo - plo;
        int pos_hi = base + total_lo + ihi - phi;
        int jb_lo = lane * 64, jb_hi = (64 + lane) * 64;
        while (lo) {
            int bt = __builtin_ctzll(lo);
            out_idx[pos_lo++] = jb_lo + bt;
            lo &= lo - 1;
        }
        while (hi) {
            int bt = __builtin_ctzll(hi);
            out_idx[pos_hi++] = jb_hi + bt;
            hi &= hi - 1;
        }
    }

    // ---- tail fill [L, C0) (K1 fills [C0, 64M)) ----
    int Lr = (L + 3) & ~3;
    if (b == 0 && t < (Lr - L)) out_idx[L + t] = -1;
    int4* out4 = (int4*)out_idx;
    const int4 v = make_int4(-1, -1, -1, -1);
    int i = (Lr >> 2) + b * 256 + t;
    const int stride = 2048 * 256;
    for (; i < C04; i += stride) out4[i] = v;
}

// ====================== generic fallback (round-1 path) ======================

__global__ __launch_bounds__(256) void fill_kernel(int* __restrict__ out, size_t total) {
    size_t n4 = total >> 2;
    int4* out4 = (int4*)out;
    size_t i = (size_t)blockIdx.x * blockDim.x + threadIdx.x;
    size_t stride = (size_t)gridDim.x * blockDim.x;
    const int4 v = make_int4(-1, -1, -1, -1);
    for (; i < n4; i += stride) out4[i] = v;
    if (blockIdx.x == 0 && threadIdx.x == 0) {
        for (size_t k = n4 << 2; k < total; ++k) out[k] = -1;
    }
}

__global__ __launch_bounds__(256) void count_kernel(
    const float* __restrict__ data, const float* __restrict__ queries,
    const float* __restrict__ radius_p, int n, int m, int* __restrict__ counts) {
    int q = (blockIdx.x * blockDim.x + threadIdx.x) >> 6;
    int lane = threadIdx.x & 63;
    if (q >= m) return;
    float r = radius_p[0];
    float T = sq_threshold(r);
    float qx = queries[3 * q + 0], qy = queries[3 * q + 1], qz = queries[3 * q + 2];
    float q2 = __fadd_rn(__fadd_rn(__fmul_rn(qx, qx), __fmul_rn(qy, qy)),
                         __fmul_rn(qz, qz));
    int cnt = 0;
    for (int j = lane; j < n; j += 64) {
        float u = pair_metric(qx, qy, qz, q2, data[3 * j], data[3 * j + 1], data[3 * j + 2]);
        if (u <= T) cnt++;
    }
    for (int off = 32; off > 0; off >>= 1) cnt += __shfl_down(cnt, off, 64);
    if (lane == 0) counts[q] = cnt;
}

__global__ __launch_bounds__(1024) void scan_kernel2(const int* __restrict__ counts,
                                                     int* __restrict__ rs, int m) {
    __shared__ int part[1024];
    int t = threadIdx.x;
    int base = t * 8;
    int c[8];
    int s = 0;
    for (int k = 0; k < 8; ++k) {
        int p = base + k;
        c[k] = (p < m) ? counts[p] : 0;
        s += c[k];
    }
    part[t] = s;
    __syncthreads();
    for (int off = 1; off < 1024; off <<= 1) {
        int v = 0;
        if (t >= off) v = part[t - off];
        __syncthreads();
        if (t >= off) part[t] += v;
        __syncthreads();
    }
    int run = (t == 0) ? 0 : part[t - 1];
    for (int k = 0; k < 8; ++k) {
        int p = base + k;
        if (p < m) rs[p] = run;
        run += c[k];
    }
    if (t == 1023) rs[m] = part[1023];
}

__global__ __launch_bounds__(256) void emit_kernel(
    const float* __restrict__ data, const float* __restrict__ queries,
    const float* __restrict__ radius_p, int n, int m,
    const int* __restrict__ row_splits, int* __restrict__ out_idx) {
    int q = (blockIdx.x * blockDim.x + threadIdx.x) >> 6;
    int lane = threadIdx.x & 63;
    if (q >= m) return;
    float r = radius_p[0];
    float T = sq_threshold(r);
    float qx = queries[3 * q + 0], qy = queries[3 * q + 1], qz = queries[3 * q + 2];
    float q2 = __fadd_rn(__fadd_rn(__fmul_rn(qx, qx), __fmul_rn(qy, qy)),
                         __fmul_rn(qz, qz));
    int base = row_splits[q];
    unsigned long long lane_mask_lt = (lane == 0) ? 0ULL : (~0ULL >> (64 - lane));
    for (int j0 = 0; j0 < n; j0 += 64) {
        int j = j0 + lane;
        bool pred = false;
        if (j < n) {
            float u = pair_metric(qx, qy, qz, q2, data[3 * j], data[3 * j + 1], data[3 * j + 2]);
            pred = (u <= T);
        }
        unsigned long long mask = __ballot(pred);
        if (pred) {
            int pos = base + __popcll(mask & lane_mask_lt);
            out_idx[pos] = j;
        }
        base += __popcll(mask);
    }
}

// ===========================================================================

extern "C" void kernel_launch(void* const* d_in, const int* in_sizes, int n_in,
                              void* d_out, int out_size, void* d_ws, size_t ws_size,
                              hipStream_t stream) {
    const float* data = (const float*)d_in[0];
    const float* queries = (const float*)d_in[1];
    const float* radius = (const float*)d_in[2];
    int n = in_sizes[0] / 3;
    int m = in_sizes[1] / 3;
    int* out = (int*)d_out;
    size_t idx_count = (size_t)m * (size_t)n;
    int* row = out + idx_count;  // m+1 ints

    // ws layout: masks (8MB, query-major) | counts (32KB)
    size_t mask_bytes = (size_t)N8 * 128 * 8;
    size_t need = mask_bytes + N8 * 4;
    bool fast = (n == N8) && (m == N8) && (ws_size >= need);

    if (fast) {
        unsigned long long* masks = (unsigned long long*)d_ws;
        int* counts = (int*)((char*)d_ws + mask_bytes);
        hipMemsetAsync(counts, 0, N8 * sizeof(int), stream);
        fused_interleave<<<2048, 256, 0, stream>>>(data, queries, radius, out,
                                                   masks, counts);
        scanemit_fill_tail<<<2048, 256, 0, stream>>>(masks, counts, out, row);
    } else {
        fill_kernel<<<2048, 256, 0, stream>>>(out, idx_count);
        int blocks = (m * 64 + 255) / 256;
        count_kernel<<<blocks, 256, 0, stream>>>(data, queries, radius, n, m, row);
        scan_kernel2<<<1, 1024, 0, stream>>>(row, row, m);
        emit_kernel<<<blocks, 256, 0, stream>>>(data, queries, radius, n, m, row, out);
    }
}